// Round 16
// baseline (2144.632 us; speedup 1.0000x reference)
//
#include <hip/hip_runtime.h>
#include <cstdint>
#include <cstddef>

// Problem sizes (fixed)
#define B_ 16
#define S_ 256
#define V_ 32000
#define D_ 512
#define H_ 512
#define T_ 50
#define KX (T_ + D_)        // 562  input width
#define KXP 576             // padded to 18*32 for MFMA K-loop
#define G4 (4 * H_)         // 2048 gate width
#define M_ (B_ * S_)        // 4096 rows

#define GBLK 64             // persistent LSTM blocks
#define NWRK 448            // dense worker blocks (2 blocks/CU occupancy)
#define UPB 8               // h-units per lstm block
#define HST 512             // LDS K-stride (h tile) in u16
#define NJT 32              // dense m-tiles (4096/128)
#define NNT 250             // dense n-tiles (32000/128)
#define NTILE (NJT * NNT)

typedef unsigned short u16;
typedef unsigned int u32;
typedef __attribute__((ext_vector_type(8))) short bf16x8;
typedef __attribute__((ext_vector_type(4))) float f32x4;
typedef __attribute__((ext_vector_type(4))) u16 u16x4;
typedef __attribute__((ext_vector_type(8))) u16 u16x8;
typedef __attribute__((ext_vector_type(4))) u32 u32x4;

__device__ __forceinline__ float sigmoidf_(float x) { return 1.f / (1.f + expf(-x)); }

__device__ __forceinline__ u16 f2bf_rne(float x) {
  u32 u = __float_as_uint(x);
  u32 r = (u + 0x7fffu + ((u >> 16) & 1u)) >> 16;
  return (u16)r;
}
__device__ __forceinline__ float bf2f(u16 h) { return __uint_as_float(((u32)h) << 16); }

// LDS swizzle (bijective per row): XOR index bits 3..5 with row&7.
__device__ __forceinline__ int swz(int row, int k) {
  return row * HST + (k ^ ((row & 7) << 3));
}

#define GLD_LDS16(g, l) __builtin_amdgcn_global_load_lds( \
    (const __attribute__((address_space(1))) void*)(g), \
    (__attribute__((address_space(3))) void*)(l), 16, 0, 0)

// ---------------------------------------------------------------------------
// gather+split: X[m][k] = concat(topic[m], emb[tok[m]])[k] (pad 562..575 = 0)
// ---------------------------------------------------------------------------
__global__ __launch_bounds__(256) void gather_split_x(
    const int* __restrict__ tokens, const float* __restrict__ topic,
    const float* __restrict__ embed, u16* __restrict__ Xhi,
    u16* __restrict__ Xlo) {
  const int m = blockIdx.x;
  const int tok = tokens[m];
  const int k4 = threadIdx.x * 4;
  if (k4 >= KXP) return;
  u16x4 hv, lv;
  #pragma unroll
  for (int i = 0; i < 4; ++i) {
    int k = k4 + i;
    float v = 0.f;
    if (k < T_)       v = topic[(size_t)m * T_ + k];
    else if (k < KX)  v = embed[(size_t)tok * D_ + (k - T_)];
    u16 h = f2bf_rne(v);
    hv[i] = h;
    lv[i] = f2bf_rne(v - bf2f(h));
  }
  size_t o = (size_t)m * KXP + k4;
  *(u16x4*)(Xhi + o) = hv;
  *(u16x4*)(Xlo + o) = lv;
}

// ---------------------------------------------------------------------------
// Wx [562][2048] fp32 -> Wxt hi/lo [2048][576] bf16 (transposed, split, pad 0)
// ---------------------------------------------------------------------------
__global__ __launch_bounds__(256) void wx_split_t(
    const float* __restrict__ W, u16* __restrict__ Whi, u16* __restrict__ Wlo) {
  __shared__ float tile[32][33];
  const int n0 = blockIdx.x * 32, k0 = blockIdx.y * 32;
  const int r = threadIdx.x >> 3;
  const int c4 = (threadIdx.x & 7) * 4;
  const int kg = k0 + r;
  const float* src = W + (size_t)kg * G4 + n0 + c4;
  #pragma unroll
  for (int i = 0; i < 4; ++i) tile[r][c4 + i] = (kg < KX) ? src[i] : 0.f;
  __syncthreads();
  u16x4 hv, lv;
  #pragma unroll
  for (int i = 0; i < 4; ++i) {
    float x = tile[c4 + i][r];
    u16 h = f2bf_rne(x);
    hv[i] = h;
    lv[i] = f2bf_rne(x - bf2f(h));
  }
  size_t o = (size_t)(n0 + r) * KXP + k0 + c4;
  *(u16x4*)(Whi + o) = hv;
  *(u16x4*)(Wlo + o) = lv;
}

// ---------------------------------------------------------------------------
// proj MFMA: xs_proj[M][2048] = X[M][576] @ Wxt[2048][576]^T + lb
// ---------------------------------------------------------------------------
__global__ __launch_bounds__(256) void proj_mfma(
    const u16* __restrict__ Ahi, const u16* __restrict__ Alo,
    const u16* __restrict__ Bhi, const u16* __restrict__ Blo,
    const float* __restrict__ bias, float* __restrict__ C) {
  __shared__ u16 lds[4][128 * 32];
  const int tid = threadIdx.x;
  const int w = tid >> 6, lane = tid & 63;
  const int bm = blockIdx.y * 128;
  const int bn = blockIdx.x * 128;
  const int wm = (w >> 1) * 64, wn = (w & 1) * 64;

  f32x4 acc[4][4];
  #pragma unroll
  for (int m = 0; m < 4; ++m)
    #pragma unroll
    for (int n = 0; n < 4; ++n) acc[m][n] = (f32x4){0.f, 0.f, 0.f, 0.f};

  const u16* src0 = Ahi + (size_t)bm * KXP;
  const u16* src1 = Alo + (size_t)bm * KXP;
  const u16* src2 = Bhi + (size_t)bn * KXP;
  const u16* src3 = Blo + (size_t)bn * KXP;

  const int lrow = lane >> 2;
  const int lkb  = (lane & 3) * 8;
  const int kb   = (lane >> 4) * 8;

  for (int k0 = 0; k0 < KXP; k0 += 32) {
    #pragma unroll
    for (int cc = 0; cc < 2; ++cc) {
      const int c = w * 2 + cc;
      const int row = c * 16 + lrow;
      const size_t goff = (size_t)row * KXP + k0 + lkb;
      u16* l = &lds[0][0] + c * 16 * 32;
      GLD_LDS16(src0 + goff, l);
      GLD_LDS16(src1 + goff, l + 128 * 32);
      GLD_LDS16(src2 + goff, l + 2 * 128 * 32);
      GLD_LDS16(src3 + goff, l + 3 * 128 * 32);
    }
    __syncthreads();

    bf16x8 ah[4], al[4], bh[4], bl[4];
    #pragma unroll
    for (int m = 0; m < 4; ++m) {
      int r = wm + m * 16 + (lane & 15);
      ah[m] = *(const bf16x8*)&lds[0][r * 32 + kb];
      al[m] = *(const bf16x8*)&lds[1][r * 32 + kb];
    }
    #pragma unroll
    for (int n = 0; n < 4; ++n) {
      int r = wn + n * 16 + (lane & 15);
      bh[n] = *(const bf16x8*)&lds[2][r * 32 + kb];
      bl[n] = *(const bf16x8*)&lds[3][r * 32 + kb];
    }
    #pragma unroll
    for (int m = 0; m < 4; ++m)
      #pragma unroll
      for (int n = 0; n < 4; ++n) {
        acc[m][n] = __builtin_amdgcn_mfma_f32_16x16x32_bf16(al[m], bh[n], acc[m][n], 0, 0, 0);
        acc[m][n] = __builtin_amdgcn_mfma_f32_16x16x32_bf16(ah[m], bl[n], acc[m][n], 0, 0, 0);
        acc[m][n] = __builtin_amdgcn_mfma_f32_16x16x32_bf16(ah[m], bh[n], acc[m][n], 0, 0, 0);
      }
    __syncthreads();
  }

  const int lc = lane & 15, lr4 = (lane >> 4) * 4;
  #pragma unroll
  for (int n = 0; n < 4; ++n) {
    int col = bn + wn + n * 16 + lc;
    float bv = bias[col];
    #pragma unroll
    for (int m = 0; m < 4; ++m) {
      int row0 = bm + wm + m * 16 + lr4;
      float* Cp = C + (size_t)row0 * G4 + col;
      #pragma unroll
      for (int j = 0; j < 4; ++j)
        Cp[(size_t)j * G4] = acc[m][n][j] + bv;
    }
  }
}

// ---------------------------------------------------------------------------
// Split dense_w [512][V] fp32 -> Whi/Wlo [V][512] bf16 (transposed, split)
// ---------------------------------------------------------------------------
__global__ __launch_bounds__(256) void split_w_t(
    const float* __restrict__ W, u16* __restrict__ Whi, u16* __restrict__ Wlo) {
  __shared__ float tile[32][33];
  const int n0 = blockIdx.x * 32, k0 = blockIdx.y * 32;
  const int r = threadIdx.x >> 3;
  const int c4 = (threadIdx.x & 7) * 4;
  const float* src = W + (size_t)(k0 + r) * V_ + n0 + c4;
  #pragma unroll
  for (int i = 0; i < 4; ++i) tile[r][c4 + i] = src[i];
  __syncthreads();
  u16x4 hv, lv;
  #pragma unroll
  for (int i = 0; i < 4; ++i) {
    float x = tile[c4 + i][r];
    u16 h = f2bf_rne(x);
    hv[i] = h;
    lv[i] = f2bf_rne(x - bf2f(h));
  }
  size_t o = (size_t)(n0 + r) * 512 + k0 + c4;
  *(u16x4*)(Whi + o) = hv;
  *(u16x4*)(Wlo + o) = lv;
}

// ---------------------------------------------------------------------------
// LDS union: lstm (h tile + zpart; weights now in REGISTERS) ~40.5 KB,
// dense (r12 single-buffered 128x128 staging) 32 KB -> block LDS ~41 KB
// -> with __launch_bounds__(256,2): 2 blocks/CU.
// ---------------------------------------------------------------------------
union SharedMem {
  struct {
    u16 hhi[16 * HST];
    u16 hlo[16 * HST];
    float zpart[4][16][34];
  } lstm;
  struct {
    u16 Ah[128 * 32];
    u16 Al[128 * 32];
    u16 Bh[128 * 32];
    u16 Bl[128 * 32];
  } dense;
};

// ---------------------------------------------------------------------------
// FUSED persistent LSTM + progressive dense GEMM. 512 blocks, 256 threads,
// 2 blocks/CU (the r12-r15 bottleneck was 1 block/CU -> zero cross-block TLP
// for the workers; barrier-synced K-loops can't hide staging latency within
// one block).
// Blocks 0..63: r6 LSTM; weight fragments are step-invariant per lane ->
//   preloaded ONCE into 64 VGPRs (16 x bf16x8), freeing 64 KB LDS.
// Blocks 64..511: r12-verbatim dense workers (128x128 tiles, serial K-loop)
//   pulling tiles from a DYNAMIC atomic work queue (robust to any residency:
//   resident workers drain the queue; late blocks get nothing).
// ---------------------------------------------------------------------------
__global__ __launch_bounds__(256, 2) void fused_lstm_dense(
    const float* __restrict__ xs_proj, const float* __restrict__ Wh,
    u32* __restrict__ hpk,                          // [2][16][512] packed
    u32* __restrict__ Apk,                          // [M_][512] packed, s-major
    u32* __restrict__ ctr,                          // [0]=step ctr, [64]=work queue
    const u16* __restrict__ Bhi, const u16* __restrict__ Blo,
    const float* __restrict__ bias, float* __restrict__ out) {
  __shared__ SharedMem sm;
  __shared__ u32 tshare;

  const int bid = blockIdx.x;
  const int tid = threadIdx.x;
  const int w = tid >> 6;
  const int lane = tid & 63;

  if (bid < GBLK) {
    // ================= LSTM (r6 structure, weights in registers) ===========
    const int u0 = bid * UPB;
    const int kb = (lane >> 4) * 8;
    const int l15 = lane & 15;

    // one-time weight fragment preload (step-invariant; 16 x bf16x8 = 64 VGPR)
    bf16x8 wb0h[4], wb0l[4], wb1h[4], wb1l[4];
    {
      const int gc0 = ((l15 >> 3) * 512) + u0 + (l15 & 7);        // gates i,j
      const int gc1 = ((2 + (l15 >> 3)) * 512) + u0 + (l15 & 7);  // gates f,o
      #pragma unroll
      for (int ks = 0; ks < 4; ++ks) {
        const int kB = w * 128 + ks * 32 + kb;
        #pragma unroll
        for (int j = 0; j < 8; ++j) {
          float v0 = Wh[(size_t)(kB + j) * G4 + gc0];
          u16 h0 = f2bf_rne(v0);
          wb0h[ks][j] = (short)h0;
          wb0l[ks][j] = (short)f2bf_rne(v0 - bf2f(h0));
          float v1 = Wh[(size_t)(kB + j) * G4 + gc1];
          u16 h1 = f2bf_rne(v1);
          wb1h[ks][j] = (short)h1;
          wb1l[ks][j] = (short)f2bf_rne(v1 - bf2f(h1));
        }
      }
    }

    float c_reg = 0.f;
    const int rb = tid >> 3;
    const int rj = tid & 7;

    for (int s = 0; s < S_; ++s) {
      float zi = 0.f, zj2 = 0.f, zf = 0.f, zo = 0.f;
      if (tid < 128) {
        const float* zp = xs_proj + ((size_t)rb * S_ + s) * G4 + u0 + rj;
        zi = zp[0]; zj2 = zp[512]; zf = zp[1024]; zo = zp[1536];
      }

      if (s > 0) {
        if (tid == 0) {
          const u32 tgt = 64u * (u32)s;
          while (__hip_atomic_load(ctr, __ATOMIC_RELAXED,
                                   __HIP_MEMORY_SCOPE_AGENT) < tgt)
            __builtin_amdgcn_s_sleep(1);
        }
        __syncthreads();
        asm volatile("" ::: "memory");
      }

      {
        const u32* src = hpk + (size_t)(s & 1) * 8192;
        u32 v[32];
        #pragma unroll
        for (int j = 0; j < 32; ++j)
          v[j] = __hip_atomic_load(src + tid + j * 256, __ATOMIC_RELAXED,
                                   __HIP_MEMORY_SCOPE_AGENT);
        #pragma unroll
        for (int j = 0; j < 32; ++j) {
          int idx = tid + j * 256;
          int b = idx >> 9, u = idx & 511;
          int si = swz(b, u);
          sm.lstm.hhi[si] = (u16)(v[j] & 0xffffu);
          sm.lstm.hlo[si] = (u16)(v[j] >> 16);
        }
      }
      __syncthreads();

      {
        f32x4 acc0 = {0.f, 0.f, 0.f, 0.f};
        f32x4 acc1 = {0.f, 0.f, 0.f, 0.f};
        #pragma unroll
        for (int ks = 0; ks < 4; ++ks) {
          const int k = w * 128 + ks * 32 + kb;
          const int ia = swz(l15, k);
          bf16x8 ah = *(const bf16x8*)&sm.lstm.hhi[ia];
          bf16x8 al = *(const bf16x8*)&sm.lstm.hlo[ia];
          acc0 = __builtin_amdgcn_mfma_f32_16x16x32_bf16(al, wb0h[ks], acc0, 0, 0, 0);
          acc0 = __builtin_amdgcn_mfma_f32_16x16x32_bf16(ah, wb0l[ks], acc0, 0, 0, 0);
          acc0 = __builtin_amdgcn_mfma_f32_16x16x32_bf16(ah, wb0h[ks], acc0, 0, 0, 0);
          acc1 = __builtin_amdgcn_mfma_f32_16x16x32_bf16(al, wb1h[ks], acc1, 0, 0, 0);
          acc1 = __builtin_amdgcn_mfma_f32_16x16x32_bf16(ah, wb1l[ks], acc1, 0, 0, 0);
          acc1 = __builtin_amdgcn_mfma_f32_16x16x32_bf16(ah, wb1h[ks], acc1, 0, 0, 0);
        }
        #pragma unroll
        for (int jj = 0; jj < 4; ++jj) {
          int r = (lane >> 4) * 4 + jj;
          sm.lstm.zpart[w][r][l15] = acc0[jj];
          sm.lstm.zpart[w][r][16 + l15] = acc1[jj];
        }
      }
      __syncthreads();

      if (tid < 128) {
        #pragma unroll
        for (int ww = 0; ww < 4; ++ww) {
          zi  += sm.lstm.zpart[ww][rb][rj];
          zj2 += sm.lstm.zpart[ww][rb][8 + rj];
          zf  += sm.lstm.zpart[ww][rb][16 + rj];
          zo  += sm.lstm.zpart[ww][rb][24 + rj];
        }
        float cc = sigmoidf_(zf) * c_reg + sigmoidf_(zi) * tanhf(zj2);
        c_reg = cc;
        float h = sigmoidf_(zo) * tanhf(cc);
        u16 hh = f2bf_rne(h);
        u16 hl = f2bf_rne(h - bf2f(hh));
        u32 pack = (u32)hh | ((u32)hl << 16);
        const int hoff = rb * 512 + u0 + rj;
        __hip_atomic_store(hpk + (size_t)((s + 1) & 1) * 8192 + hoff, pack,
                           __ATOMIC_RELAXED, __HIP_MEMORY_SCOPE_AGENT);
        const size_t ar = ((size_t)s * 16 + rb) * 512 + u0 + rj;  // s-major
        __hip_atomic_store(Apk + ar, pack,
                           __ATOMIC_RELAXED, __HIP_MEMORY_SCOPE_AGENT);
      }
      asm volatile("s_waitcnt vmcnt(0)" ::: "memory");
      __syncthreads();

      if (tid == 0)   // arrive EVERY step (s=255 unlocks dense tile jt=31)
        __hip_atomic_fetch_add(ctr, 1u, __ATOMIC_RELAXED,
                               __HIP_MEMORY_SCOPE_AGENT);
    }
  } else {
    // ================= dense workers (r12 structure + dynamic queue) =======
    u32* wq = ctr + 64;                    // separate cacheline
    const int wm = (w >> 1) * 64, wn = (w & 1) * 64;
    const int l15 = lane & 15;
    const int kb = (lane >> 4) * 8;
    const int lrow = lane >> 2;
    const int lkb = (lane & 3) * 8;
    const int r_ = tid >> 1;
    const int kh = (tid & 1) * 16;

    int lastj = -1;
    for (;;) {
      if (tid == 0)
        tshare = __hip_atomic_fetch_add(wq, 1u, __ATOMIC_RELAXED,
                                        __HIP_MEMORY_SCOPE_AGENT);
      __syncthreads();
      const u32 t = tshare;
      if (t >= (u32)NTILE) break;
      const int jt = (int)(t / NNT);
      const int n  = (int)(t - (u32)jt * NNT);
      if (jt != lastj) {
        if (tid == 0) {
          const u32 tgt = 512u * (u32)(jt + 1);
          while (__hip_atomic_load(ctr, __ATOMIC_RELAXED,
                                   __HIP_MEMORY_SCOPE_AGENT) < tgt)
            __builtin_amdgcn_s_sleep(32);
        }
        __syncthreads();
        asm volatile("" ::: "memory");
        lastj = jt;
      }

      const int bmA = jt * 128;
      const int bn = n * 128;
      f32x4 acc[4][4];
      #pragma unroll
      for (int m = 0; m < 4; ++m)
        #pragma unroll
        for (int q = 0; q < 4; ++q) acc[m][q] = (f32x4){0.f, 0.f, 0.f, 0.f};

      const u16* srcBh = Bhi + (size_t)bn * 512;
      const u16* srcBl = Blo + (size_t)bn * 512;

      for (int k0 = 0; k0 < 512; k0 += 32) {
        // A stage: plain u32 loads + unpack + ds_write (r12 pattern)
        {
          const u32* ap = Apk + (size_t)(bmA + r_) * 512 + k0 + kh;
          u32x4 a0 = *(const u32x4*)(ap);
          u32x4 a1 = *(const u32x4*)(ap + 4);
          u32x4 a2 = *(const u32x4*)(ap + 8);
          u32x4 a3 = *(const u32x4*)(ap + 12);
          u16x8 h0, h1, l0, l1;
          #pragma unroll
          for (int i = 0; i < 4; ++i) {
            h0[i]   = (u16)(a0[i] & 0xffffu); l0[i]   = (u16)(a0[i] >> 16);
            h0[4+i] = (u16)(a1[i] & 0xffffu); l0[4+i] = (u16)(a1[i] >> 16);
            h1[i]   = (u16)(a2[i] & 0xffffu); l1[i]   = (u16)(a2[i] >> 16);
            h1[4+i] = (u16)(a3[i] & 0xffffu); l1[4+i] = (u16)(a3[i] >> 16);
          }
          *(u16x8*)&sm.dense.Ah[r_ * 32 + kh]     = h0;
          *(u16x8*)&sm.dense.Ah[r_ * 32 + kh + 8] = h1;
          *(u16x8*)&sm.dense.Al[r_ * 32 + kh]     = l0;
          *(u16x8*)&sm.dense.Al[r_ * 32 + kh + 8] = l1;
        }
        // B stage: global_load_lds (linear LDS)
        #pragma unroll
        for (int cc = 0; cc < 2; ++cc) {
          const int c = w * 2 + cc;
          const int row = c * 16 + lrow;
          const size_t goff = (size_t)row * 512 + k0 + lkb;
          GLD_LDS16(srcBh + goff, &sm.dense.Bh[c * 16 * 32]);
          GLD_LDS16(srcBl + goff, &sm.dense.Bl[c * 16 * 32]);
        }
        __syncthreads();

        bf16x8 ah[4], al[4], bh[4], bl[4];
        #pragma unroll
        for (int m = 0; m < 4; ++m) {
          int r = wm + m * 16 + l15;
          ah[m] = *(const bf16x8*)&sm.dense.Ah[r * 32 + kb];
          al[m] = *(const bf16x8*)&sm.dense.Al[r * 32 + kb];
        }
        #pragma unroll
        for (int q = 0; q < 4; ++q) {
          int r = wn + q * 16 + l15;
          bh[q] = *(const bf16x8*)&sm.dense.Bh[r * 32 + kb];
          bl[q] = *(const bf16x8*)&sm.dense.Bl[r * 32 + kb];
        }
        #pragma unroll
        for (int m = 0; m < 4; ++m)
          #pragma unroll
          for (int q = 0; q < 4; ++q) {
            acc[m][q] = __builtin_amdgcn_mfma_f32_16x16x32_bf16(al[m], bh[q], acc[m][q], 0, 0, 0);
            acc[m][q] = __builtin_amdgcn_mfma_f32_16x16x32_bf16(ah[m], bl[q], acc[m][q], 0, 0, 0);
            acc[m][q] = __builtin_amdgcn_mfma_f32_16x16x32_bf16(ah[m], bh[q], acc[m][q], 0, 0, 0);
          }
        __syncthreads();
      }

      // epilogue: decode s-major rows -> out[b*256+s]
      const int lc = lane & 15, lr4 = (lane >> 4) * 4;
      #pragma unroll
      for (int q = 0; q < 4; ++q) {
        int col = bn + wn + q * 16 + lc;
        float bv = bias[col];
        #pragma unroll
        for (int m = 0; m < 4; ++m) {
          int mbase = bmA + wm + m * 16;      // aligned 16: one s per fragment
          int s = mbase >> 4;
          float* Cp = out + ((size_t)lr4 * 256 + s) * V_ + col;
          #pragma unroll
          for (int jj = 0; jj < 4; ++jj)
            Cp[(size_t)jj * 256 * V_] = acc[m][q][jj] + bv;
        }
      }
    }
  }
}

// ---------------------------------------------------------------------------
extern "C" void kernel_launch(void* const* d_in, const int* in_sizes, int n_in,
                              void* d_out, int out_size, void* d_ws, size_t ws_size,
                              hipStream_t stream) {
  const int*   tokens = (const int*)  d_in[0];
  const float* topic  = (const float*)d_in[1];
  const float* embed  = (const float*)d_in[2];
  const float* lk     = (const float*)d_in[3];   // [1074, 2048]
  const float* lb     = (const float*)d_in[4];   // [2048]
  const float* dw     = (const float*)d_in[5];   // [512, 32000]
  const float* db     = (const float*)d_in[6];   // [32000]
  float* out = (float*)d_out;                    // [4096, 32000]

  char* ws = (char*)d_ws;
  size_t off = 0;
  float* xs_proj = (float*)(ws + off); off += (size_t)M_ * G4 * 4;   // 33.5 MB
  // X region (proj inputs) aliases Apk (lstm output): sequential lifetimes
  char* xa = ws + off;                 // region size = max(9.44MB, 8.39MB)
  u16* Xhi = (u16*)xa;
  u16* Xlo = (u16*)(xa + (size_t)M_ * KXP * 2);
  u32* Apk = (u32*)xa;
  off += (size_t)M_ * KXP * 2 * 2;                                   //  9.4 MB
  u16* Whi = (u16*)(ws + off); off += (size_t)V_ * 512 * 2;          // 32.8 MB
  u16* Wlo = (u16*)(ws + off); off += (size_t)V_ * 512 * 2;          // 32.8 MB
  u16* Wxhi = (u16*)(ws + off); off += (size_t)G4 * KXP * 2;         //  2.4 MB
  u16* Wxlo = (u16*)(ws + off); off += (size_t)G4 * KXP * 2;         //  2.4 MB
  u32* hpk = (u32*)(ws + off); off += 2 * 8192 * 4;                  // 64 KB
  u32* ctr = (u32*)(ws + off); off += 512;   // [0]=step ctr, [64]=work queue

  // zero h double-buffer, step counter and work queue every call (replay-safe)
  hipMemsetAsync(hpk, 0, 2 * 8192 * 4, stream);
  hipMemsetAsync(ctr, 0, 512, stream);

  // 1. dense-W split+transpose; Wx split+transpose; X gather+split
  hipLaunchKernelGGL(split_w_t, dim3(V_ / 32, 512 / 32), dim3(256), 0, stream,
                     dw, Whi, Wlo);
  hipLaunchKernelGGL(wx_split_t, dim3(G4 / 32, KXP / 32), dim3(256), 0, stream,
                     lk, Wxhi, Wxlo);
  hipLaunchKernelGGL(gather_split_x, dim3(M_), dim3(256), 0, stream,
                     tokens, topic, embed, Xhi, Xlo);

  // 2. input projection (split-bf16 MFMA)
  hipLaunchKernelGGL(proj_mfma, dim3(G4 / 128, M_ / 128), dim3(256), 0, stream,
                     Xhi, Xlo, Wxhi, Wxlo, lb, xs_proj);

  // 3. fused persistent LSTM + progressive dense logits GEMM
  const float* Wh = lk + (size_t)KX * G4;
  hipLaunchKernelGGL(fused_lstm_dense, dim3(GBLK + NWRK), dim3(256), 0, stream,
                     xs_proj, Wh, hpk, Apk, ctr, Whi, Wlo, db, out);
}

// Round 17
// 1185.904 us; speedup vs baseline: 1.8084x; 1.8084x over previous
//
#include <hip/hip_runtime.h>
#include <cstdint>
#include <cstddef>

// Problem sizes (fixed)
#define B_ 16
#define S_ 256
#define V_ 32000
#define D_ 512
#define H_ 512
#define T_ 50
#define KX (T_ + D_)        // 562  input width
#define KXP 576             // padded to 18*32 for MFMA K-loop
#define G4 (4 * H_)         // 2048 gate width
#define M_ (B_ * S_)        // 4096 rows

#define GBLK 64             // persistent LSTM blocks
#define NWRK 192            // dense worker blocks (64..255)
#define UPB 8               // h-units per lstm block
#define WST 512             // LDS K-stride in u16
#define NJT 32              // dense m-tiles (4096/128)
#define NNT 250             // dense n-tiles (32000/128)

typedef unsigned short u16;
typedef unsigned int u32;
typedef __attribute__((ext_vector_type(8))) short bf16x8;
typedef __attribute__((ext_vector_type(4))) float f32x4;
typedef __attribute__((ext_vector_type(4))) u16 u16x4;
typedef __attribute__((ext_vector_type(8))) u16 u16x8;
typedef __attribute__((ext_vector_type(4))) u32 u32x4;

__device__ __forceinline__ float sigmoidf_(float x) { return 1.f / (1.f + expf(-x)); }

__device__ __forceinline__ u16 f2bf_rne(float x) {
  u32 u = __float_as_uint(x);
  u32 r = (u + 0x7fffu + ((u >> 16) & 1u)) >> 16;
  return (u16)r;
}
__device__ __forceinline__ float bf2f(u16 h) { return __uint_as_float(((u32)h) << 16); }

// LDS swizzle (bijective per row): XOR index bits 3..5 with row&7.
__device__ __forceinline__ int swz(int row, int k) {
  return row * WST + (k ^ ((row & 7) << 3));
}

#define GLD_LDS16(g, l) __builtin_amdgcn_global_load_lds( \
    (const __attribute__((address_space(1))) void*)(g), \
    (__attribute__((address_space(3))) void*)(l), 16, 0, 0)

// ---------------------------------------------------------------------------
// gather+split: X[m][k] = concat(topic[m], emb[tok[m]])[k] (pad 562..575 = 0)
// ---------------------------------------------------------------------------
__global__ __launch_bounds__(256) void gather_split_x(
    const int* __restrict__ tokens, const float* __restrict__ topic,
    const float* __restrict__ embed, u16* __restrict__ Xhi,
    u16* __restrict__ Xlo) {
  const int m = blockIdx.x;
  const int tok = tokens[m];
  const int k4 = threadIdx.x * 4;
  if (k4 >= KXP) return;
  u16x4 hv, lv;
  #pragma unroll
  for (int i = 0; i < 4; ++i) {
    int k = k4 + i;
    float v = 0.f;
    if (k < T_)       v = topic[(size_t)m * T_ + k];
    else if (k < KX)  v = embed[(size_t)tok * D_ + (k - T_)];
    u16 h = f2bf_rne(v);
    hv[i] = h;
    lv[i] = f2bf_rne(v - bf2f(h));
  }
  size_t o = (size_t)m * KXP + k4;
  *(u16x4*)(Xhi + o) = hv;
  *(u16x4*)(Xlo + o) = lv;
}

// ---------------------------------------------------------------------------
// Wx [562][2048] fp32 -> Wxt hi/lo [2048][576] bf16 (transposed, split, pad 0)
// ---------------------------------------------------------------------------
__global__ __launch_bounds__(256) void wx_split_t(
    const float* __restrict__ W, u16* __restrict__ Whi, u16* __restrict__ Wlo) {
  __shared__ float tile[32][33];
  const int n0 = blockIdx.x * 32, k0 = blockIdx.y * 32;
  const int r = threadIdx.x >> 3;
  const int c4 = (threadIdx.x & 7) * 4;
  const int kg = k0 + r;
  const float* src = W + (size_t)kg * G4 + n0 + c4;
  #pragma unroll
  for (int i = 0; i < 4; ++i) tile[r][c4 + i] = (kg < KX) ? src[i] : 0.f;
  __syncthreads();
  u16x4 hv, lv;
  #pragma unroll
  for (int i = 0; i < 4; ++i) {
    float x = tile[c4 + i][r];
    u16 h = f2bf_rne(x);
    hv[i] = h;
    lv[i] = f2bf_rne(x - bf2f(h));
  }
  size_t o = (size_t)(n0 + r) * KXP + k0 + c4;
  *(u16x4*)(Whi + o) = hv;
  *(u16x4*)(Wlo + o) = lv;
}

// ---------------------------------------------------------------------------
// proj MFMA: xs_proj[M][2048] = X[M][576] @ Wxt[2048][576]^T + lb
// ---------------------------------------------------------------------------
__global__ __launch_bounds__(256) void proj_mfma(
    const u16* __restrict__ Ahi, const u16* __restrict__ Alo,
    const u16* __restrict__ Bhi, const u16* __restrict__ Blo,
    const float* __restrict__ bias, float* __restrict__ C) {
  __shared__ u16 lds[4][128 * 32];
  const int tid = threadIdx.x;
  const int w = tid >> 6, lane = tid & 63;
  const int bm = blockIdx.y * 128;
  const int bn = blockIdx.x * 128;
  const int wm = (w >> 1) * 64, wn = (w & 1) * 64;

  f32x4 acc[4][4];
  #pragma unroll
  for (int m = 0; m < 4; ++m)
    #pragma unroll
    for (int n = 0; n < 4; ++n) acc[m][n] = (f32x4){0.f, 0.f, 0.f, 0.f};

  const u16* src0 = Ahi + (size_t)bm * KXP;
  const u16* src1 = Alo + (size_t)bm * KXP;
  const u16* src2 = Bhi + (size_t)bn * KXP;
  const u16* src3 = Blo + (size_t)bn * KXP;

  const int lrow = lane >> 2;
  const int lkb  = (lane & 3) * 8;
  const int kb   = (lane >> 4) * 8;

  for (int k0 = 0; k0 < KXP; k0 += 32) {
    #pragma unroll
    for (int cc = 0; cc < 2; ++cc) {
      const int c = w * 2 + cc;
      const int row = c * 16 + lrow;
      const size_t goff = (size_t)row * KXP + k0 + lkb;
      u16* l = &lds[0][0] + c * 16 * 32;
      GLD_LDS16(src0 + goff, l);
      GLD_LDS16(src1 + goff, l + 128 * 32);
      GLD_LDS16(src2 + goff, l + 2 * 128 * 32);
      GLD_LDS16(src3 + goff, l + 3 * 128 * 32);
    }
    __syncthreads();

    bf16x8 ah[4], al[4], bh[4], bl[4];
    #pragma unroll
    for (int m = 0; m < 4; ++m) {
      int r = wm + m * 16 + (lane & 15);
      ah[m] = *(const bf16x8*)&lds[0][r * 32 + kb];
      al[m] = *(const bf16x8*)&lds[1][r * 32 + kb];
    }
    #pragma unroll
    for (int n = 0; n < 4; ++n) {
      int r = wn + n * 16 + (lane & 15);
      bh[n] = *(const bf16x8*)&lds[2][r * 32 + kb];
      bl[n] = *(const bf16x8*)&lds[3][r * 32 + kb];
    }
    #pragma unroll
    for (int m = 0; m < 4; ++m)
      #pragma unroll
      for (int n = 0; n < 4; ++n) {
        acc[m][n] = __builtin_amdgcn_mfma_f32_16x16x32_bf16(al[m], bh[n], acc[m][n], 0, 0, 0);
        acc[m][n] = __builtin_amdgcn_mfma_f32_16x16x32_bf16(ah[m], bl[n], acc[m][n], 0, 0, 0);
        acc[m][n] = __builtin_amdgcn_mfma_f32_16x16x32_bf16(ah[m], bh[n], acc[m][n], 0, 0, 0);
      }
    __syncthreads();
  }

  const int lc = lane & 15, lr4 = (lane >> 4) * 4;
  #pragma unroll
  for (int n = 0; n < 4; ++n) {
    int col = bn + wn + n * 16 + lc;
    float bv = bias[col];
    #pragma unroll
    for (int m = 0; m < 4; ++m) {
      int row0 = bm + wm + m * 16 + lr4;
      float* Cp = C + (size_t)row0 * G4 + col;
      #pragma unroll
      for (int j = 0; j < 4; ++j)
        Cp[(size_t)j * G4] = acc[m][n][j] + bv;
    }
  }
}

// ---------------------------------------------------------------------------
// Split dense_w [512][V] fp32 -> Whi/Wlo [V][512] bf16 (transposed, split)
// ---------------------------------------------------------------------------
__global__ __launch_bounds__(256) void split_w_t(
    const float* __restrict__ W, u16* __restrict__ Whi, u16* __restrict__ Wlo) {
  __shared__ float tile[32][33];
  const int n0 = blockIdx.x * 32, k0 = blockIdx.y * 32;
  const int r = threadIdx.x >> 3;
  const int c4 = (threadIdx.x & 7) * 4;
  const float* src = W + (size_t)(k0 + r) * V_ + n0 + c4;
  #pragma unroll
  for (int i = 0; i < 4; ++i) tile[r][c4 + i] = src[i];
  __syncthreads();
  u16x4 hv, lv;
  #pragma unroll
  for (int i = 0; i < 4; ++i) {
    float x = tile[c4 + i][r];
    u16 h = f2bf_rne(x);
    hv[i] = h;
    lv[i] = f2bf_rne(x - bf2f(h));
  }
  size_t o = (size_t)(n0 + r) * 512 + k0 + c4;
  *(u16x4*)(Whi + o) = hv;
  *(u16x4*)(Wlo + o) = lv;
}

// ---------------------------------------------------------------------------
// FUSED persistent LSTM + progressive dense GEMM. 256 blocks, 256 threads.
// Blocks 0..63: r6 LSTM (relaxed MALL counter sync). h published to hpk dbuf
//   and Apk s-major; arrive every step.
// Blocks 64..255: dense workers, r10 SELF-PACED tile sweep (t = wid + k*192,
//   j-major order): workers lag the unlock wave and stream at their own pace.
//   This is the measured optimum (r12 = 1189us); all perturbations tested in
//   r13-r16 (m-doubling, throttling, pipelining, occupancy raising) regressed.
// Coherence: Apk write-once via sc1 before the gated arrive (vmcnt(0)+bar);
//   workers first-touch after the gate -> plain cached reads see final data;
//   kernel-boundary invalidation covers replays and the X/Apk aliasing.
// ---------------------------------------------------------------------------
__global__ __launch_bounds__(256, 1) void fused_lstm_dense(
    const float* __restrict__ xs_proj, const float* __restrict__ Wh,
    u32* __restrict__ hpk,                          // [2][16][512] packed
    u32* __restrict__ Apk,                          // [M_][512] packed, s-major
    u32* __restrict__ ctr,
    const u16* __restrict__ Bhi, const u16* __restrict__ Blo,
    const float* __restrict__ bias, float* __restrict__ out) {
  // lstm LDS
  __shared__ u16 whi_l[32 * WST];
  __shared__ u16 wlo_l[32 * WST];
  __shared__ u16 hhi_l[16 * WST];
  __shared__ u16 hlo_l[16 * WST];
  __shared__ float zpart[4][16][34];
  // dense LDS
  __shared__ u16 Ah_l[128 * 32];
  __shared__ u16 Al_l[128 * 32];
  __shared__ u16 Bh_l[128 * 32];
  __shared__ u16 Bl_l[128 * 32];

  const int bid = blockIdx.x;
  const int tid = threadIdx.x;
  const int w = tid >> 6;
  const int lane = tid & 63;

  if (bid < GBLK) {
    // ================= LSTM (r6 verbatim + Apk publish + final arrive) ======
    const int u0 = bid * UPB;

    for (int idx = tid; idx < 32 * 512; idx += 256) {
      int c = idx & 31, k = idx >> 5;
      int gc = (c >> 3) * 512 + u0 + (c & 7);
      float v = Wh[(size_t)k * G4 + gc];
      u16 hi = f2bf_rne(v);
      int si = swz(c, k);
      whi_l[si] = hi;
      wlo_l[si] = f2bf_rne(v - bf2f(hi));
    }

    float c_reg = 0.f;
    const int rb = tid >> 3;
    const int rj = tid & 7;
    const int kb = (lane >> 4) * 8;
    const int l15 = lane & 15;

    for (int s = 0; s < S_; ++s) {
      float zi = 0.f, zj2 = 0.f, zf = 0.f, zo = 0.f;
      if (tid < 128) {
        const float* zp = xs_proj + ((size_t)rb * S_ + s) * G4 + u0 + rj;
        zi = zp[0]; zj2 = zp[512]; zf = zp[1024]; zo = zp[1536];
      }

      if (s > 0) {
        if (tid == 0) {
          const u32 tgt = 64u * (u32)s;
          while (__hip_atomic_load(ctr, __ATOMIC_RELAXED,
                                   __HIP_MEMORY_SCOPE_AGENT) < tgt)
            __builtin_amdgcn_s_sleep(1);
        }
        __syncthreads();
        asm volatile("" ::: "memory");
      }

      {
        const u32* src = hpk + (size_t)(s & 1) * 8192;
        u32 v[32];
        #pragma unroll
        for (int j = 0; j < 32; ++j)
          v[j] = __hip_atomic_load(src + tid + j * 256, __ATOMIC_RELAXED,
                                   __HIP_MEMORY_SCOPE_AGENT);
        #pragma unroll
        for (int j = 0; j < 32; ++j) {
          int idx = tid + j * 256;
          int b = idx >> 9, u = idx & 511;
          int si = swz(b, u);
          hhi_l[si] = (u16)(v[j] & 0xffffu);
          hlo_l[si] = (u16)(v[j] >> 16);
        }
      }
      __syncthreads();

      {
        f32x4 acc0 = {0.f, 0.f, 0.f, 0.f};
        f32x4 acc1 = {0.f, 0.f, 0.f, 0.f};
        #pragma unroll
        for (int ks = 0; ks < 4; ++ks) {
          const int k = w * 128 + ks * 32 + kb;
          const int ia = swz(l15, k);
          const int ib = swz(16 + l15, k);
          bf16x8 ah  = *(const bf16x8*)&hhi_l[ia];
          bf16x8 al  = *(const bf16x8*)&hlo_l[ia];
          bf16x8 b0h = *(const bf16x8*)&whi_l[ia];
          bf16x8 b0l = *(const bf16x8*)&wlo_l[ia];
          bf16x8 b1h = *(const bf16x8*)&whi_l[ib];
          bf16x8 b1l = *(const bf16x8*)&wlo_l[ib];
          acc0 = __builtin_amdgcn_mfma_f32_16x16x32_bf16(al, b0h, acc0, 0, 0, 0);
          acc0 = __builtin_amdgcn_mfma_f32_16x16x32_bf16(ah, b0l, acc0, 0, 0, 0);
          acc0 = __builtin_amdgcn_mfma_f32_16x16x32_bf16(ah, b0h, acc0, 0, 0, 0);
          acc1 = __builtin_amdgcn_mfma_f32_16x16x32_bf16(al, b1h, acc1, 0, 0, 0);
          acc1 = __builtin_amdgcn_mfma_f32_16x16x32_bf16(ah, b1l, acc1, 0, 0, 0);
          acc1 = __builtin_amdgcn_mfma_f32_16x16x32_bf16(ah, b1h, acc1, 0, 0, 0);
        }
        #pragma unroll
        for (int jj = 0; jj < 4; ++jj) {
          int r = (lane >> 4) * 4 + jj;
          zpart[w][r][l15] = acc0[jj];
          zpart[w][r][16 + l15] = acc1[jj];
        }
      }
      __syncthreads();

      if (tid < 128) {
        #pragma unroll
        for (int ww = 0; ww < 4; ++ww) {
          zi  += zpart[ww][rb][rj];
          zj2 += zpart[ww][rb][8 + rj];
          zf  += zpart[ww][rb][16 + rj];
          zo  += zpart[ww][rb][24 + rj];
        }
        float cc = sigmoidf_(zf) * c_reg + sigmoidf_(zi) * tanhf(zj2);
        c_reg = cc;
        float h = sigmoidf_(zo) * tanhf(cc);
        u16 hh = f2bf_rne(h);
        u16 hl = f2bf_rne(h - bf2f(hh));
        u32 pack = (u32)hh | ((u32)hl << 16);
        const int hoff = rb * 512 + u0 + rj;
        __hip_atomic_store(hpk + (size_t)((s + 1) & 1) * 8192 + hoff, pack,
                           __ATOMIC_RELAXED, __HIP_MEMORY_SCOPE_AGENT);
        const size_t ar = ((size_t)s * 16 + rb) * 512 + u0 + rj;  // s-major
        __hip_atomic_store(Apk + ar, pack,
                           __ATOMIC_RELAXED, __HIP_MEMORY_SCOPE_AGENT);
      }
      asm volatile("s_waitcnt vmcnt(0)" ::: "memory");
      __syncthreads();

      if (tid == 0)   // arrive EVERY step (s=255 unlocks dense tile jt=31)
        __hip_atomic_fetch_add(ctr, 1u, __ATOMIC_RELAXED,
                               __HIP_MEMORY_SCOPE_AGENT);
    }
  } else {
    // ================= dense workers (r10 self-paced sweep) ================
    const int wid = bid - GBLK;            // 0..191
    const int wm = (w >> 1) * 64, wn = (w & 1) * 64;
    const int l15 = lane & 15;
    const int kb = (lane >> 4) * 8;
    const int lrow = lane >> 2;
    const int lkb = (lane & 3) * 8;
    const int r_ = tid >> 1;
    const int kh = (tid & 1) * 16;

    int lastj = -1;
    for (int t = wid; t < NJT * NNT; t += NWRK) {
      const int jt = t / NNT;
      const int n  = t - jt * NNT;
      if (jt != lastj) {
        if (tid == 0) {
          const u32 tgt = 512u * (u32)(jt + 1);
          while (__hip_atomic_load(ctr, __ATOMIC_RELAXED,
                                   __HIP_MEMORY_SCOPE_AGENT) < tgt)
            __builtin_amdgcn_s_sleep(32);
        }
        __syncthreads();
        asm volatile("" ::: "memory");
        lastj = jt;
      }

      const int bmA = jt * 128;
      const int bn = n * 128;
      f32x4 acc[4][4];
      #pragma unroll
      for (int m = 0; m < 4; ++m)
        #pragma unroll
        for (int q = 0; q < 4; ++q) acc[m][q] = (f32x4){0.f, 0.f, 0.f, 0.f};

      const u16* srcBh = Bhi + (size_t)bn * 512;
      const u16* srcBl = Blo + (size_t)bn * 512;

      for (int k0 = 0; k0 < 512; k0 += 32) {
        // A stage: plain u32 loads + unpack + ds_write
        {
          const u32* ap = Apk + (size_t)(bmA + r_) * 512 + k0 + kh;
          u32x4 a0 = *(const u32x4*)(ap);
          u32x4 a1 = *(const u32x4*)(ap + 4);
          u32x4 a2 = *(const u32x4*)(ap + 8);
          u32x4 a3 = *(const u32x4*)(ap + 12);
          u16x8 h0, h1, l0, l1;
          #pragma unroll
          for (int i = 0; i < 4; ++i) {
            h0[i]   = (u16)(a0[i] & 0xffffu); l0[i]   = (u16)(a0[i] >> 16);
            h0[4+i] = (u16)(a1[i] & 0xffffu); l0[4+i] = (u16)(a1[i] >> 16);
            h1[i]   = (u16)(a2[i] & 0xffffu); l1[i]   = (u16)(a2[i] >> 16);
            h1[4+i] = (u16)(a3[i] & 0xffffu); l1[4+i] = (u16)(a3[i] >> 16);
          }
          *(u16x8*)&Ah_l[r_ * 32 + kh]     = h0;
          *(u16x8*)&Ah_l[r_ * 32 + kh + 8] = h1;
          *(u16x8*)&Al_l[r_ * 32 + kh]     = l0;
          *(u16x8*)&Al_l[r_ * 32 + kh + 8] = l1;
        }
        // B stage: global_load_lds (linear LDS)
        #pragma unroll
        for (int cc = 0; cc < 2; ++cc) {
          const int c = w * 2 + cc;
          const int row = c * 16 + lrow;
          const size_t goff = (size_t)row * 512 + k0 + lkb;
          GLD_LDS16(srcBh + goff, &Bh_l[c * 16 * 32]);
          GLD_LDS16(srcBl + goff, &Bl_l[c * 16 * 32]);
        }
        __syncthreads();

        bf16x8 ah[4], al[4], bh[4], bl[4];
        #pragma unroll
        for (int m = 0; m < 4; ++m) {
          int r = wm + m * 16 + l15;
          ah[m] = *(const bf16x8*)&Ah_l[r * 32 + kb];
          al[m] = *(const bf16x8*)&Al_l[r * 32 + kb];
        }
        #pragma unroll
        for (int q = 0; q < 4; ++q) {
          int r = wn + q * 16 + l15;
          bh[q] = *(const bf16x8*)&Bh_l[r * 32 + kb];
          bl[q] = *(const bf16x8*)&Bl_l[r * 32 + kb];
        }
        #pragma unroll
        for (int m = 0; m < 4; ++m)
          #pragma unroll
          for (int q = 0; q < 4; ++q) {
            acc[m][q] = __builtin_amdgcn_mfma_f32_16x16x32_bf16(al[m], bh[q], acc[m][q], 0, 0, 0);
            acc[m][q] = __builtin_amdgcn_mfma_f32_16x16x32_bf16(ah[m], bl[q], acc[m][q], 0, 0, 0);
            acc[m][q] = __builtin_amdgcn_mfma_f32_16x16x32_bf16(ah[m], bh[q], acc[m][q], 0, 0, 0);
          }
        __syncthreads();
      }

      // epilogue: decode s-major rows -> out[b*256+s]
      const int lc = lane & 15, lr4 = (lane >> 4) * 4;
      #pragma unroll
      for (int q = 0; q < 4; ++q) {
        int col = bn + wn + q * 16 + lc;
        float bv = bias[col];
        #pragma unroll
        for (int m = 0; m < 4; ++m) {
          int mbase = bmA + wm + m * 16;      // aligned 16: one s per fragment
          int s = mbase >> 4;
          float* Cp = out + ((size_t)lr4 * 256 + s) * V_ + col;
          #pragma unroll
          for (int jj = 0; jj < 4; ++jj)
            Cp[(size_t)jj * 256 * V_] = acc[m][q][jj] + bv;
        }
      }
    }
  }
}

// ---------------------------------------------------------------------------
extern "C" void kernel_launch(void* const* d_in, const int* in_sizes, int n_in,
                              void* d_out, int out_size, void* d_ws, size_t ws_size,
                              hipStream_t stream) {
  const int*   tokens = (const int*)  d_in[0];
  const float* topic  = (const float*)d_in[1];
  const float* embed  = (const float*)d_in[2];
  const float* lk     = (const float*)d_in[3];   // [1074, 2048]
  const float* lb     = (const float*)d_in[4];   // [2048]
  const float* dw     = (const float*)d_in[5];   // [512, 32000]
  const float* db     = (const float*)d_in[6];   // [32000]
  float* out = (float*)d_out;                    // [4096, 32000]

  char* ws = (char*)d_ws;
  size_t off = 0;
  float* xs_proj = (float*)(ws + off); off += (size_t)M_ * G4 * 4;   // 33.5 MB
  // X region (proj inputs) aliases Apk (lstm output): sequential lifetimes
  char* xa = ws + off;                 // region size = max(9.44MB, 8.39MB)
  u16* Xhi = (u16*)xa;
  u16* Xlo = (u16*)(xa + (size_t)M_ * KXP * 2);
  u32* Apk = (u32*)xa;
  off += (size_t)M_ * KXP * 2 * 2;                                   //  9.4 MB
  u16* Whi = (u16*)(ws + off); off += (size_t)V_ * 512 * 2;          // 32.8 MB
  u16* Wlo = (u16*)(ws + off); off += (size_t)V_ * 512 * 2;          // 32.8 MB
  u16* Wxhi = (u16*)(ws + off); off += (size_t)G4 * KXP * 2;         //  2.4 MB
  u16* Wxlo = (u16*)(ws + off); off += (size_t)G4 * KXP * 2;         //  2.4 MB
  u32* hpk = (u32*)(ws + off); off += 2 * 8192 * 4;                  // 64 KB
  u32* ctr = (u32*)(ws + off); off += 256;

  // zero h double-buffer and step counter every call (replay-safe)
  hipMemsetAsync(hpk, 0, 2 * 8192 * 4, stream);
  hipMemsetAsync(ctr, 0, 256, stream);

  // 1. dense-W split+transpose; Wx split+transpose; X gather+split
  hipLaunchKernelGGL(split_w_t, dim3(V_ / 32, 512 / 32), dim3(256), 0, stream,
                     dw, Whi, Wlo);
  hipLaunchKernelGGL(wx_split_t, dim3(G4 / 32, KXP / 32), dim3(256), 0, stream,
                     lk, Wxhi, Wxlo);
  hipLaunchKernelGGL(gather_split_x, dim3(M_), dim3(256), 0, stream,
                     tokens, topic, embed, Xhi, Xlo);

  // 2. input projection (split-bf16 MFMA)
  hipLaunchKernelGGL(proj_mfma, dim3(G4 / 128, M_ / 128), dim3(256), 0, stream,
                     Xhi, Xlo, Wxhi, Wxlo, lb, xs_proj);

  // 3. fused persistent LSTM + progressive dense logits GEMM
  const float* Wh = lk + (size_t)KX * G4;
  hipLaunchKernelGGL(fused_lstm_dense, dim3(GBLK + NWRK), dim3(256), 0, stream,
                     xs_proj, Wh, hpk, Apk, ctr, Whi, Wlo, db, out);
}